// Round 13
// baseline (95.982 us; speedup 1.0000x reference)
//
#include <hip/hip_runtime.h>
#include <hip/hip_bf16.h>

// Poincare pairwise distance, c=1:
//   d(x,p) = acosh(1 + 2*||x-p||^2 / ((1-||x||^2)(1-||p||^2)))
// B=16384, N=4096, D=64. Output 16384x4096 f32 (256 MiB) -> write-bound.
//
// Round 13 = Round 12 byte-identical EXCEPT output stores are
// __builtin_nontemporal_store (streaming / no-allocate). Hypothesis D:
// the output stream's L2 write-allocate evicts the proto/emb ws images,
// forcing ~96MB of staging reads to HBM that contend with the writeback
// stream ((256+96)/6.9 ~ 51us + overheads = the observed 61us invariant).
// nt stores keep L2 read-hot -> HBM traffic ~ 256MB + compulsory.

constexpr int BATCH = 16384;
constexpr int NCON  = 4096;
constexpr int DIM   = 64;
constexpr int TM    = 256;
constexpr int TN    = 128;

// ws layout (bytes), 16B-aligned (identical bytes to rounds 6/8/10/12):
constexpr size_t WS_EMB   = 0;                        // 2 MiB  (bf16 swizzled emb images)
constexpr size_t WS_PROTO = (size_t)2 << 20;          // 512 KiB (bf16 swizzled proto images)
constexpr size_t WS_X2    = WS_PROTO + (512u << 10);  // f32[16384]
constexpr size_t WS_CROW  = WS_X2   + 64u * 1024;     // f32[16384]
constexpr size_t WS_P2    = WS_CROW + 64u * 1024;     // f32[4096]
constexpr size_t WS_RP    = WS_P2   + 16u * 1024;     // f32[4096]

typedef float  f32x4  __attribute__((ext_vector_type(4)));
typedef __bf16 bf16x8 __attribute__((ext_vector_type(8)));

// ---------------- pre-pass (unchanged from rounds 6/8/10/12) ----------------
__global__ __launch_bounds__(256)
void prepass_kernel(const float* __restrict__ emb,
                    const float* __restrict__ proto,
                    char* __restrict__ ws)
{
    int gid = blockIdx.x * 256 + threadIdx.x;
    if (gid < 131072) {
        int c = gid;
        int mt = c >> 9, within = c & 511;          // 64-row half-tiles
        int e0  = within * 8;
        int row = e0 >> 6;
        int k0  = (e0 & 63) ^ ((row & 7) << 3);
        const float* src = emb + (size_t)(mt * 64 + row) * DIM + k0;
        f32x4 a = *reinterpret_cast<const f32x4*>(src);
        f32x4 b = *reinterpret_cast<const f32x4*>(src + 4);
        bf16x8 v;
        v[0]=(__bf16)a.x; v[1]=(__bf16)a.y; v[2]=(__bf16)a.z; v[3]=(__bf16)a.w;
        v[4]=(__bf16)b.x; v[5]=(__bf16)b.y; v[6]=(__bf16)b.z; v[7]=(__bf16)b.w;
        *reinterpret_cast<bf16x8*>(ws + WS_EMB + (size_t)c * 16) = v;
    } else if (gid < 163840) {
        int c = gid - 131072;
        int nt = c >> 10, within = c & 1023;        // 128-row tiles
        int e0  = within * 8;
        int row = e0 >> 6;
        int k0  = (e0 & 63) ^ ((row & 7) << 3);
        const float* src = proto + (size_t)(nt * 128 + row) * DIM + k0;
        f32x4 a = *reinterpret_cast<const f32x4*>(src);
        f32x4 b = *reinterpret_cast<const f32x4*>(src + 4);
        bf16x8 v;
        v[0]=(__bf16)a.x; v[1]=(__bf16)a.y; v[2]=(__bf16)a.z; v[3]=(__bf16)a.w;
        v[4]=(__bf16)b.x; v[5]=(__bf16)b.y; v[6]=(__bf16)b.z; v[7]=(__bf16)b.w;
        *reinterpret_cast<bf16x8*>(ws + WS_PROTO + (size_t)c * 16) = v;
    } else if (gid < 180224) {
        int r = gid - 163840;
        const f32x4* src = reinterpret_cast<const f32x4*>(emb + (size_t)r * DIM);
        float s = 0.0f;
        #pragma unroll
        for (int i = 0; i < 16; ++i) {
            f32x4 v = src[i];
            s += v.x*v.x + v.y*v.y + v.z*v.z + v.w*v.w;
        }
        reinterpret_cast<float*>(ws + WS_X2)[r]   = s;
        reinterpret_cast<float*>(ws + WS_CROW)[r] = 2.0f * __builtin_amdgcn_rcpf(1.0f - s);
    } else if (gid < 184320) {
        int r = gid - 180224;
        const f32x4* src = reinterpret_cast<const f32x4*>(proto + (size_t)r * DIM);
        float s = 0.0f;
        #pragma unroll
        for (int i = 0; i < 16; ++i) {
            f32x4 v = src[i];
            s += v.x*v.x + v.y*v.y + v.z*v.z + v.w*v.w;
        }
        reinterpret_cast<float*>(ws + WS_P2)[r] = s;
        reinterpret_cast<float*>(ws + WS_RP)[r] = __builtin_amdgcn_rcpf(1.0f - s);
    }
}

// ---------------- main kernel ----------------
// Grid 2048 = 64 m-tiles x 32 n-tiles. mt owned by one XCD; 8 consecutive
// blocks within an XCD share nt. 4 waves; wave owns 64 emb rows x 128
// protos. 2 blocks/CU.
__global__ __launch_bounds__(256, 2)
void poincare_pairwise_kernel(const char* __restrict__ ws,
                              float* __restrict__ out)
{
    __shared__ __bf16 As[TM * DIM];   // 32 KiB (emb tile image)
    __shared__ __bf16 Bs[TN * DIM];   // 16 KiB (proto tile image)

    const int tid = threadIdx.x;
    const int bid = blockIdx.x;
    const int xcd = bid & 7;
    const int q   = bid >> 3;          // 0..255
    const int mt  = xcd * 8 + (q & 7); // 0..63, one XCD per mt
    const int nt  = q >> 3;            // 0..31
    const int m0  = mt * TM;
    const int n0  = nt * TN;

    // ---------- staging: pure linear uint4 copy ----------
    {
        const uint4* esrc = reinterpret_cast<const uint4*>(ws + WS_EMB + (size_t)mt * 32768);
        uint4* edst = reinterpret_cast<uint4*>(As);
        #pragma unroll
        for (int i = 0; i < 8; ++i)
            edst[i * 256 + tid] = esrc[i * 256 + tid];
        const uint4* psrc = reinterpret_cast<const uint4*>(ws + WS_PROTO + (size_t)nt * 16384);
        uint4* pdst = reinterpret_cast<uint4*>(Bs);
        #pragma unroll
        for (int i = 0; i < 4; ++i)
            pdst[i * 256 + tid] = psrc[i * 256 + tid];
    }

    const int lane = tid & 63;
    const int wid  = tid >> 6;         // wave -> 64-row emb strip
    const int lr   = lane & 15;
    const int g    = lane >> 4;
    const int lk   = g * 8;

    // per-lane row params (issued while staging is in flight)
    float  x2[4], crow[4];
    float* rowp[4];
    #pragma unroll
    for (int rf = 0; rf < 4; ++rf) {
        int xrow = wid * 64 + rf * 16 + lr;
        x2[rf]   = reinterpret_cast<const float*>(ws + WS_X2)[m0 + xrow];
        crow[rf] = reinterpret_cast<const float*>(ws + WS_CROW)[m0 + xrow];
        rowp[rf] = out + (size_t)(m0 + xrow) * NCON + n0;
    }

    __syncthreads();   // the ONLY barrier

    // ---------- MFMA: wave = 64 emb rows x 128 protos ----------
    bf16x8 xfrag[4][2];                // [rf][kk]
    #pragma unroll
    for (int rf = 0; rf < 4; ++rf) {
        int xrow = wid * 64 + rf * 16 + lr;
        #pragma unroll
        for (int kk = 0; kk < 2; ++kk) {
            int ke = (kk * 32 + lk) ^ ((xrow & 7) << 3);
            xfrag[rf][kk] = *reinterpret_cast<const bf16x8*>(&As[xrow * DIM + ke]);
        }
    }
    f32x4 acc[4][8] = {};              // [rf][pf]
    #pragma unroll
    for (int kk = 0; kk < 2; ++kk) {
        bf16x8 pfrag[8];
        #pragma unroll
        for (int pf = 0; pf < 8; ++pf) {
            int prow = pf * 16 + lr;
            int kep  = (kk * 32 + lk) ^ ((prow & 7) << 3);
            pfrag[pf] = *reinterpret_cast<const bf16x8*>(&Bs[prow * DIM + kep]);
        }
        #pragma unroll
        for (int pf = 0; pf < 8; ++pf)
            #pragma unroll
            for (int rf = 0; rf < 4; ++rf)
                acc[rf][pf] = __builtin_amdgcn_mfma_f32_16x16x32_bf16(
                    pfrag[pf], xfrag[rf][kk], acc[rf][pf], 0, 0, 0);
    }

    // ---------- epilogue: poly acosh + NONTEMPORAL store ----------
    // D layout: col = lane&15 -> emb row (lr); row = g*4+j -> proto idx.
    // d = sqrt(tt) * P(tt), P cubic fit of acosh(1+t)/sqrt(t) on [0,4].
    const float* p2a = reinterpret_cast<const float*>(ws + WS_P2) + n0;
    const float* rpa = reinterpret_cast<const float*>(ws + WS_RP) + n0;
    #pragma unroll
    for (int pf = 0; pf < 8; ++pf) {
        int   col = pf * 16 + g * 4;
        f32x4 p2  = *reinterpret_cast<const f32x4*>(p2a + col);
        f32x4 rp  = *reinterpret_cast<const f32x4*>(rpa + col);
        #pragma unroll
        for (int rf = 0; rf < 4; ++rf) {
            f32x4 dv;
            #pragma unroll
            for (int j = 0; j < 4; ++j) {
                float sq = fmaxf(x2[rf] + p2[j] - 2.0f * acc[rf][pf][j], 0.0f);
                float tt = sq * (crow[rf] * rp[j]);
                float u  = __builtin_amdgcn_sqrtf(tt);
                float pl = fmaf(fmaf(fmaf(-0.0013415f, tt, 0.0164700f),
                                     tt, -0.1113059f),
                                tt, 1.4134377f);
                dv[j]    = u * pl;
            }
            __builtin_nontemporal_store(dv, reinterpret_cast<f32x4*>(rowp[rf] + col));
        }
    }
}

extern "C" void kernel_launch(void* const* d_in, const int* in_sizes, int n_in,
                              void* d_out, int out_size, void* d_ws, size_t ws_size,
                              hipStream_t stream) {
    const float* emb   = (const float*)d_in[0];
    const float* proto = (const float*)d_in[1];
    float* out = (float*)d_out;
    char* ws   = (char*)d_ws;

    prepass_kernel<<<720, 256, 0, stream>>>(emb, proto, ws);    // 184320 threads
    poincare_pairwise_kernel<<<2048, 256, 0, stream>>>(ws, out); // 64 m x 32 n
}

// Round 14
// 60.716 us; speedup vs baseline: 1.5808x; 1.5808x over previous
//
#include <hip/hip_runtime.h>
#include <hip/hip_bf16.h>

// Poincare pairwise distance, c=1:
//   d(x,p) = acosh(1 + 2*||x-p||^2 / ((1-||x||^2)(1-||p||^2)))
// B=16384, N=4096, D=64. Output 16384x4096 f32 (256 MiB) -> write-bound.
//
// Round 14 = Round 12 + FULL-LINE stores via LDS epilogue transpose.
// Theory: write path is L2-transaction-rate capped. R12's store pattern is
// 64B per row per instruction (half of a 128B L2 line) -> 74k txn/us x 64B
// = 4.7 TB/s, vs fill kernel 54k txn/us x 128B = 6.9 TB/s. Epilogue now
// routes each 64-row x 128-col chunk through LDS (swizzled, aliases dead
// As) so each wave store instruction writes 2 rows x 512B contiguous
// (8 full 128B lines).

constexpr int BATCH = 16384;
constexpr int NCON  = 4096;
constexpr int DIM   = 64;
constexpr int TM    = 256;
constexpr int TN    = 128;

// ws layout (bytes), 16B-aligned (identical bytes to rounds 6/8/10/12):
constexpr size_t WS_EMB   = 0;                        // 2 MiB  (bf16 swizzled emb images)
constexpr size_t WS_PROTO = (size_t)2 << 20;          // 512 KiB (bf16 swizzled proto images)
constexpr size_t WS_X2    = WS_PROTO + (512u << 10);  // f32[16384]
constexpr size_t WS_CROW  = WS_X2   + 64u * 1024;     // f32[16384]
constexpr size_t WS_P2    = WS_CROW + 64u * 1024;     // f32[4096]
constexpr size_t WS_RP    = WS_P2   + 16u * 1024;     // f32[4096]

typedef float  f32x4  __attribute__((ext_vector_type(4)));
typedef __bf16 bf16x8 __attribute__((ext_vector_type(8)));

// ---------------- pre-pass (unchanged from rounds 6/8/10/12) ----------------
__global__ __launch_bounds__(256)
void prepass_kernel(const float* __restrict__ emb,
                    const float* __restrict__ proto,
                    char* __restrict__ ws)
{
    int gid = blockIdx.x * 256 + threadIdx.x;
    if (gid < 131072) {
        int c = gid;
        int mt = c >> 9, within = c & 511;          // 64-row half-tiles
        int e0  = within * 8;
        int row = e0 >> 6;
        int k0  = (e0 & 63) ^ ((row & 7) << 3);
        const float* src = emb + (size_t)(mt * 64 + row) * DIM + k0;
        f32x4 a = *reinterpret_cast<const f32x4*>(src);
        f32x4 b = *reinterpret_cast<const f32x4*>(src + 4);
        bf16x8 v;
        v[0]=(__bf16)a.x; v[1]=(__bf16)a.y; v[2]=(__bf16)a.z; v[3]=(__bf16)a.w;
        v[4]=(__bf16)b.x; v[5]=(__bf16)b.y; v[6]=(__bf16)b.z; v[7]=(__bf16)b.w;
        *reinterpret_cast<bf16x8*>(ws + WS_EMB + (size_t)c * 16) = v;
    } else if (gid < 163840) {
        int c = gid - 131072;
        int nt = c >> 10, within = c & 1023;        // 128-row tiles
        int e0  = within * 8;
        int row = e0 >> 6;
        int k0  = (e0 & 63) ^ ((row & 7) << 3);
        const float* src = proto + (size_t)(nt * 128 + row) * DIM + k0;
        f32x4 a = *reinterpret_cast<const f32x4*>(src);
        f32x4 b = *reinterpret_cast<const f32x4*>(src + 4);
        bf16x8 v;
        v[0]=(__bf16)a.x; v[1]=(__bf16)a.y; v[2]=(__bf16)a.z; v[3]=(__bf16)a.w;
        v[4]=(__bf16)b.x; v[5]=(__bf16)b.y; v[6]=(__bf16)b.z; v[7]=(__bf16)b.w;
        *reinterpret_cast<bf16x8*>(ws + WS_PROTO + (size_t)c * 16) = v;
    } else if (gid < 180224) {
        int r = gid - 163840;
        const f32x4* src = reinterpret_cast<const f32x4*>(emb + (size_t)r * DIM);
        float s = 0.0f;
        #pragma unroll
        for (int i = 0; i < 16; ++i) {
            f32x4 v = src[i];
            s += v.x*v.x + v.y*v.y + v.z*v.z + v.w*v.w;
        }
        reinterpret_cast<float*>(ws + WS_X2)[r]   = s;
        reinterpret_cast<float*>(ws + WS_CROW)[r] = 2.0f * __builtin_amdgcn_rcpf(1.0f - s);
    } else if (gid < 184320) {
        int r = gid - 180224;
        const f32x4* src = reinterpret_cast<const f32x4*>(proto + (size_t)r * DIM);
        float s = 0.0f;
        #pragma unroll
        for (int i = 0; i < 16; ++i) {
            f32x4 v = src[i];
            s += v.x*v.x + v.y*v.y + v.z*v.z + v.w*v.w;
        }
        reinterpret_cast<float*>(ws + WS_P2)[r] = s;
        reinterpret_cast<float*>(ws + WS_RP)[r] = __builtin_amdgcn_rcpf(1.0f - s);
    }
}

// ---------------- main kernel ----------------
// Grid 2048 = 64 m-tiles x 32 n-tiles. mt owned by one XCD; 8 consecutive
// blocks within an XCD share nt. 4 waves; wave owns 64 emb rows x 128
// protos. 2 blocks/CU.
__global__ __launch_bounds__(256, 2)
void poincare_pairwise_kernel(const char* __restrict__ ws,
                              float* __restrict__ out)
{
    __shared__ __align__(16) char smem[TM * DIM * 2 + TN * DIM * 2]; // 48 KiB
    __bf16* As = reinterpret_cast<__bf16*>(smem);            // 32 KiB (emb image)
    __bf16* Bs = reinterpret_cast<__bf16*>(smem + TM * DIM * 2); // 16 KiB (proto)
    float*  Es = reinterpret_cast<float*>(smem);             // 32 KiB epilogue buf
                                                             // (aliases dead As)
    const int tid = threadIdx.x;
    const int bid = blockIdx.x;
    const int xcd = bid & 7;
    const int q   = bid >> 3;          // 0..255
    const int mt  = xcd * 8 + (q & 7); // 0..63, one XCD per mt
    const int nt  = q >> 3;            // 0..31
    const int m0  = mt * TM;
    const int n0  = nt * TN;

    // ---------- staging: pure linear uint4 copy ----------
    {
        const uint4* esrc = reinterpret_cast<const uint4*>(ws + WS_EMB + (size_t)mt * 32768);
        uint4* edst = reinterpret_cast<uint4*>(As);
        #pragma unroll
        for (int i = 0; i < 8; ++i)
            edst[i * 256 + tid] = esrc[i * 256 + tid];
        const uint4* psrc = reinterpret_cast<const uint4*>(ws + WS_PROTO + (size_t)nt * 16384);
        uint4* pdst = reinterpret_cast<uint4*>(Bs);
        #pragma unroll
        for (int i = 0; i < 4; ++i)
            pdst[i * 256 + tid] = psrc[i * 256 + tid];
    }

    const int lane = tid & 63;
    const int wid  = tid >> 6;         // wave -> 64-row emb strip
    const int lr   = lane & 15;
    const int g    = lane >> 4;
    const int lk   = g * 8;

    // per-lane row params (issued while staging is in flight)
    float x2[4], crow[4];
    #pragma unroll
    for (int rf = 0; rf < 4; ++rf) {
        int xrow = wid * 64 + rf * 16 + lr;
        x2[rf]   = reinterpret_cast<const float*>(ws + WS_X2)[m0 + xrow];
        crow[rf] = reinterpret_cast<const float*>(ws + WS_CROW)[m0 + xrow];
    }
    // per-proto params, hoisted (L2-hot broadcast loads)
    f32x4 p2h[8], rph[8];
    {
        const float* p2a = reinterpret_cast<const float*>(ws + WS_P2) + n0;
        const float* rpa = reinterpret_cast<const float*>(ws + WS_RP) + n0;
        #pragma unroll
        for (int pf = 0; pf < 8; ++pf) {
            int col = pf * 16 + g * 4;
            p2h[pf] = *reinterpret_cast<const f32x4*>(p2a + col);
            rph[pf] = *reinterpret_cast<const f32x4*>(rpa + col);
        }
    }

    __syncthreads();   // staging complete

    // ---------- MFMA: wave = 64 emb rows x 128 protos ----------
    bf16x8 xfrag[4][2];                // [rf][kk]
    #pragma unroll
    for (int rf = 0; rf < 4; ++rf) {
        int xrow = wid * 64 + rf * 16 + lr;
        #pragma unroll
        for (int kk = 0; kk < 2; ++kk) {
            int ke = (kk * 32 + lk) ^ ((xrow & 7) << 3);
            xfrag[rf][kk] = *reinterpret_cast<const bf16x8*>(&As[xrow * DIM + ke]);
        }
    }
    f32x4 acc[4][8] = {};              // [rf][pf]
    #pragma unroll
    for (int kk = 0; kk < 2; ++kk) {
        bf16x8 pfrag[8];
        #pragma unroll
        for (int pf = 0; pf < 8; ++pf) {
            int prow = pf * 16 + lr;
            int kep  = (kk * 32 + lk) ^ ((prow & 7) << 3);
            pfrag[pf] = *reinterpret_cast<const bf16x8*>(&Bs[prow * DIM + kep]);
        }
        #pragma unroll
        for (int pf = 0; pf < 8; ++pf)
            #pragma unroll
            for (int rf = 0; rf < 4; ++rf)
                acc[rf][pf] = __builtin_amdgcn_mfma_f32_16x16x32_bf16(
                    pfrag[pf], xfrag[rf][kk], acc[rf][pf], 0, 0, 0);
    }

    __syncthreads();   // all LDS reads of As/Bs done -> Es may overwrite As

    // ---------- epilogue: poly acosh -> LDS transpose -> FULL-LINE stores ----
    // acc D layout: col = lane&15 -> emb row (lr); row = g*4+j -> proto idx.
    // Per rf-chunk (64 rows x 128 cols = 32 KB):
    //   write: Es[lrow][slot^(lrow&7)] (f32x4 slots; 2-way max bank alias)
    //   read : flat fi -> each wave store instr = 2 rows x 512B contiguous
    //          = 8 full 128B L2 lines.
    const int lrow = wid * 16 + lr;    // Es row for this lane
    #pragma unroll
    for (int rf = 0; rf < 4; ++rf) {
        #pragma unroll
        for (int pf = 0; pf < 8; ++pf) {
            f32x4 p2 = p2h[pf], rp = rph[pf];
            f32x4 dv;
            #pragma unroll
            for (int j = 0; j < 4; ++j) {
                float sq = fmaxf(x2[rf] + p2[j] - 2.0f * acc[rf][pf][j], 0.0f);
                float tt = sq * (crow[rf] * rp[j]);
                float u  = __builtin_amdgcn_sqrtf(tt);
                float pl = fmaf(fmaf(fmaf(-0.0013415f, tt, 0.0164700f),
                                     tt, -0.1113059f),
                                tt, 1.4134377f);
                dv[j]    = u * pl;
            }
            int slot = (pf * 4 + g) ^ (lrow & 7);
            *reinterpret_cast<f32x4*>(&Es[lrow * 128 + slot * 4]) = dv;
        }
        __syncthreads();
        #pragma unroll
        for (int it = 0; it < 8; ++it) {
            int fi = it * 256 + tid;       // 0..2047 f32x4 slots
            int r  = fi >> 5;              // Es row 0..63
            int s  = fi & 31;              // linear slot
            f32x4 v = *reinterpret_cast<const f32x4*>(&Es[r * 128 + ((s ^ (r & 7)) * 4)]);
            int grow = m0 + (r >> 4) * 64 + rf * 16 + (r & 15);
            *reinterpret_cast<f32x4*>(out + (size_t)grow * NCON + n0 + s * 4) = v;
        }
        if (rf < 3) __syncthreads();
    }
}

extern "C" void kernel_launch(void* const* d_in, const int* in_sizes, int n_in,
                              void* d_out, int out_size, void* d_ws, size_t ws_size,
                              hipStream_t stream) {
    const float* emb   = (const float*)d_in[0];
    const float* proto = (const float*)d_in[1];
    float* out = (float*)d_out;
    char* ws   = (char*)d_ws;

    prepass_kernel<<<720, 256, 0, stream>>>(emb, proto, ws);    // 184320 threads
    poincare_pairwise_kernel<<<2048, 256, 0, stream>>>(ws, out); // 64 m x 32 n
}